// Round 1
// baseline (185.081 us; speedup 1.0000x reference)
//
#include <hip/hip_runtime.h>

// Problem constants (B=1): inputs (N=32768, D=1024) f32, tag_to_token (T=128, N) f32,
// gat_mask (T, T) i32. Output (T, D) f32.
#define NTOK 32768
#define NTAG 128
#define DDIM 1024
#define TOKS_PER_BLK 64

// ---------------------------------------------------------------------------
// Kernel 1: for each token n, lastTag[n] = max{ j : t2t[j][n] > 0 } (or -1),
// and cnt[tag] = #tokens assigned to tag. Math fact: deduce_direct_string's
// temp[i][n] is 1 iff i is the LAST covering tag of n, else 0, for ANY 0/1
// coverage input — so the row-normalized t2t is one-hot per token / cnt[tag].
// ---------------------------------------------------------------------------
__global__ __launch_bounds__(256) void k_lasttag(const float* __restrict__ t2t,
                                                 int* __restrict__ lastTag,
                                                 int* __restrict__ cnt) {
    const int tid = blockIdx.x * blockDim.x + threadIdx.x;  // 0..8191
    const int n0 = tid * 4;
    int l0 = -1, l1 = -1, l2 = -1, l3 = -1;
    for (int j = 0; j < NTAG; ++j) {
        const float4 v = *reinterpret_cast<const float4*>(t2t + (size_t)j * NTOK + n0);
        if (v.x > 0.f) l0 = j;
        if (v.y > 0.f) l1 = j;
        if (v.z > 0.f) l2 = j;
        if (v.w > 0.f) l3 = j;
    }
    lastTag[n0 + 0] = l0;
    lastTag[n0 + 1] = l1;
    lastTag[n0 + 2] = l2;
    lastTag[n0 + 3] = l3;
    if (l0 >= 0) atomicAdd(&cnt[l0], 1);
    if (l1 >= 0) atomicAdd(&cnt[l1], 1);
    if (l2 >= 0) atomicAdd(&cnt[l2], 1);
    if (l3 >= 0) atomicAdd(&cnt[l3], 1);
}

// ---------------------------------------------------------------------------
// Kernel 2: segmented sum. Each block owns 64 tokens x all 1024 columns
// (thread t -> cols 4t..4t+3, float4). Tokens are walked in order; on a tag
// change the run's partial sum is flushed with 4 atomicAdds into P[tag][col].
// For the real (nested/contiguous) data each chunk is 1-2 runs, so atomics are
// rare and essentially uncontended; correctness holds for arbitrary tags.
// P is accumulated UNSCALED; the 1/cnt scaling is applied in kernel 3.
// ---------------------------------------------------------------------------
__global__ __launch_bounds__(256) void k_segsum(const float* __restrict__ inp,
                                                const int* __restrict__ lastTag,
                                                float* __restrict__ P) {
    __shared__ int tags[TOKS_PER_BLK];
    const int tid = threadIdx.x;
    const int n0 = blockIdx.x * TOKS_PER_BLK;
    if (tid < TOKS_PER_BLK) tags[tid] = lastTag[n0 + tid];
    __syncthreads();

    const int col = tid * 4;
    float4 acc = make_float4(0.f, 0.f, 0.f, 0.f);
    int cur = tags[0];
    for (int k = 0; k < TOKS_PER_BLK; ++k) {
        const int tg = tags[k];
        if (tg != cur) {  // wave-uniform branch (tags are uniform across lanes)
            if (cur >= 0) {
                float* p = P + (size_t)cur * DDIM + col;
                atomicAdd(p + 0, acc.x);
                atomicAdd(p + 1, acc.y);
                atomicAdd(p + 2, acc.z);
                atomicAdd(p + 3, acc.w);
            }
            acc = make_float4(0.f, 0.f, 0.f, 0.f);
            cur = tg;
        }
        if (tg >= 0) {
            const float4 v =
                *reinterpret_cast<const float4*>(inp + (size_t)(n0 + k) * DDIM + col);
            acc.x += v.x;
            acc.y += v.y;
            acc.z += v.z;
            acc.w += v.w;
        }
    }
    if (cur >= 0) {
        float* p = P + (size_t)cur * DDIM + col;
        atomicAdd(p + 0, acc.x);
        atomicAdd(p + 1, acc.y);
        atomicAdd(p + 2, acc.z);
        atomicAdd(p + 3, acc.w);
    }
}

// ---------------------------------------------------------------------------
// Kernel 3: triangular recurrence. deduce_child(gm) == gm for ANY input
// (inner loop provably a no-op: rows j>i are still zero at outer step i).
// The recurrence o[i] = sum_t gm[i][t] * o_cur[t]  (i = 127..0, rows > i
// already updated) is independent per column d -> one thread per column,
// column lives in LDS, per-row gm stored as two 64-bit masks (uniform across
// lanes -> LDS broadcast reads). No syncthreads needed inside the loop.
// 1/cnt row scaling is fused into the load (0 * inf = NaN matches ref's 0/0).
// ---------------------------------------------------------------------------
__global__ __launch_bounds__(64) void k_recur(const float* __restrict__ P,
                                              const int* __restrict__ gm,
                                              const int* __restrict__ cnt,
                                              float* __restrict__ out) {
    __shared__ float o[NTAG][64];              // 32 KB: this block's 64 columns
    __shared__ unsigned long long msk[NTAG][2];  // 2 KB
    __shared__ float inv[NTAG];                // 0.5 KB
    const int tid = threadIdx.x;               // 0..63
    const int col = blockIdx.x * 64 + tid;

    // Build masks + inv: 64 threads, 2 rows each.
    for (int r = tid; r < NTAG; r += 64) {
        unsigned long long m0 = 0ull, m1 = 0ull;
        const int* row = gm + r * NTAG;
        for (int t = 0; t < 64; ++t)
            if (row[t] != 0) m0 |= (1ull << t);
        for (int t = 64; t < NTAG; ++t)
            if (row[t] != 0) m1 |= (1ull << (t - 64));
        msk[r][0] = m0;
        msk[r][1] = m1;
        inv[r] = 1.0f / (float)cnt[r];
    }
    __syncthreads();

    // Load this thread's column, applying row normalization.
    for (int t = 0; t < NTAG; ++t)
        o[t][tid] = P[(size_t)t * DDIM + col] * inv[t];

    // Sequential per-column recurrence (each thread touches only [*][tid]).
    for (int i = NTAG - 1; i >= 0; --i) {
        unsigned long long m0 = msk[i][0], m1 = msk[i][1];
        float a = 0.f, b = 0.f;
        while (m0) {
            const int t = __ffsll((unsigned long long)m0) - 1;
            m0 &= (m0 - 1);
            a += o[t][tid];
        }
        while (m1) {
            const int t = __ffsll((unsigned long long)m1) + 63;
            m1 &= (m1 - 1);
            b += o[t][tid];
        }
        o[i][tid] = a + b;
    }

    for (int i = 0; i < NTAG; ++i)
        out[(size_t)i * DDIM + col] = o[i][tid];
}

// ---------------------------------------------------------------------------
extern "C" void kernel_launch(void* const* d_in, const int* in_sizes, int n_in,
                              void* d_out, int out_size, void* d_ws, size_t ws_size,
                              hipStream_t stream) {
    const float* inp = (const float*)d_in[0];   // (N, D)
    const float* t2t = (const float*)d_in[1];   // (T, N)
    const int* gm = (const int*)d_in[2];        // (T, T)
    float* out = (float*)d_out;                 // (T, D)

    char* ws = (char*)d_ws;
    float* P = (float*)ws;                          // 128*1024*4 = 524288 B
    int* cnt = (int*)(ws + 524288);                 // 512 B
    int* lastTag = (int*)(ws + 524288 + 512);       // 131072 B

    // Zero the accumulators every call (graph replays reuse d_ws).
    hipMemsetAsync(P, 0, 524288 + 512, stream);

    k_lasttag<<<NTOK / 4 / 256, 256, 0, stream>>>(t2t, lastTag, cnt);
    k_segsum<<<NTOK / TOKS_PER_BLK, 256, 0, stream>>>(inp, lastTag, P);
    k_recur<<<DDIM / 64, 64, 0, stream>>>(P, gm, cnt, out);
}

// Round 2
// 109.688 us; speedup vs baseline: 1.6873x; 1.6873x over previous
//
#include <hip/hip_runtime.h>

// Problem constants (B=1): inputs (N=32768, D=1024) f32, tag_to_token (T=128, N) f32,
// gat_mask (T, T) i32. Output (T, D) f32.
#define NTOK 32768
#define NTAG 128
#define DDIM 1024
#define TOKS_PER_BLK 32
#define ROWS_PER_CHUNK 16
#define TOK_CHUNK 1024  // tokens per block in k_lasttag (256 threads * 4)

// ---------------------------------------------------------------------------
// Kernel 1: lastTag[n] = max{ j : t2t[j][n] > 0 } (or -1).
// Math fact: deduce_direct_string's temp[i][n] is 1 iff i is the LAST covering
// tag of n (for ANY 0/1 coverage), so normalized t2t is one-hot / cnt[tag].
// Parallelized over (row-chunk, token-chunk): 8 x 32 = 256 blocks; each thread
// keeps a partial max over 16 rows (16 independent float4 loads in flight),
// then combines with atomicMax into lastTag (pre-initialized to -1).
// ---------------------------------------------------------------------------
__global__ __launch_bounds__(256) void k_lasttag(const float* __restrict__ t2t,
                                                 int* __restrict__ lastTag) {
    const int tokChunk = blockIdx.x & 31;        // 32 token chunks
    const int rowChunk = blockIdx.x >> 5;        // 8 row chunks
    const int n0 = tokChunk * TOK_CHUNK + threadIdx.x * 4;
    const int j0 = rowChunk * ROWS_PER_CHUNK;
    int l0 = -1, l1 = -1, l2 = -1, l3 = -1;
#pragma unroll
    for (int jj = 0; jj < ROWS_PER_CHUNK; ++jj) {
        const int j = j0 + jj;
        const float4 v = *reinterpret_cast<const float4*>(t2t + (size_t)j * NTOK + n0);
        if (v.x > 0.f) l0 = j;
        if (v.y > 0.f) l1 = j;
        if (v.z > 0.f) l2 = j;
        if (v.w > 0.f) l3 = j;
    }
    if (l0 >= 0) atomicMax(&lastTag[n0 + 0], l0);
    if (l1 >= 0) atomicMax(&lastTag[n0 + 1], l1);
    if (l2 >= 0) atomicMax(&lastTag[n0 + 2], l2);
    if (l3 >= 0) atomicMax(&lastTag[n0 + 3], l3);
}

// ---------------------------------------------------------------------------
// Kernel 1b: cnt[tag] histogram from lastTag (LDS histogram per block).
// ---------------------------------------------------------------------------
__global__ __launch_bounds__(256) void k_count(const int* __restrict__ lastTag,
                                               int* __restrict__ cnt) {
    __shared__ int hist[NTAG];
    const int tid = threadIdx.x;
    if (tid < NTAG) hist[tid] = 0;
    __syncthreads();
    const int n0 = blockIdx.x * TOK_CHUNK + tid * 4;
    const int4 l = *reinterpret_cast<const int4*>(lastTag + n0);
    if (l.x >= 0) atomicAdd(&hist[l.x], 1);
    if (l.y >= 0) atomicAdd(&hist[l.y], 1);
    if (l.z >= 0) atomicAdd(&hist[l.z], 1);
    if (l.w >= 0) atomicAdd(&hist[l.w], 1);
    __syncthreads();
    if (tid < NTAG && hist[tid] > 0) atomicAdd(&cnt[tid], hist[tid]);
}

// ---------------------------------------------------------------------------
// Kernel 2: segmented sum. Each block owns 32 tokens x all 1024 columns
// (thread t -> cols 4t..4t+3, float4); grid = 1024 blocks -> 16 waves/CU for
// latency hiding. Tokens walked in order; on a tag change the run's partial
// sum is flushed with 4 atomicAdds into P[tag][col]. For nested/contiguous
// data each 32-token chunk is 1-2 runs -> ~1M uncontended atomics total.
// P accumulated UNSCALED; 1/cnt applied in kernel 3.
// ---------------------------------------------------------------------------
__global__ __launch_bounds__(256) void k_segsum(const float* __restrict__ inp,
                                                const int* __restrict__ lastTag,
                                                float* __restrict__ P) {
    __shared__ int tags[TOKS_PER_BLK];
    const int tid = threadIdx.x;
    const int n0 = blockIdx.x * TOKS_PER_BLK;
    if (tid < TOKS_PER_BLK) tags[tid] = lastTag[n0 + tid];
    __syncthreads();

    const int col = tid * 4;
    float4 acc = make_float4(0.f, 0.f, 0.f, 0.f);
    int cur = tags[0];
    for (int k = 0; k < TOKS_PER_BLK; ++k) {
        const int tg = tags[k];
        if (tg != cur) {  // wave-uniform branch (tags uniform across lanes)
            if (cur >= 0) {
                float* p = P + (size_t)cur * DDIM + col;
                atomicAdd(p + 0, acc.x);
                atomicAdd(p + 1, acc.y);
                atomicAdd(p + 2, acc.z);
                atomicAdd(p + 3, acc.w);
            }
            acc = make_float4(0.f, 0.f, 0.f, 0.f);
            cur = tg;
        }
        if (tg >= 0) {
            const float4 v =
                *reinterpret_cast<const float4*>(inp + (size_t)(n0 + k) * DDIM + col);
            acc.x += v.x;
            acc.y += v.y;
            acc.z += v.z;
            acc.w += v.w;
        }
    }
    if (cur >= 0) {
        float* p = P + (size_t)cur * DDIM + col;
        atomicAdd(p + 0, acc.x);
        atomicAdd(p + 1, acc.y);
        atomicAdd(p + 2, acc.z);
        atomicAdd(p + 3, acc.w);
    }
}

// ---------------------------------------------------------------------------
// Kernel 3: triangular recurrence. deduce_child(gm) == gm for ANY input
// (inner loop provably a no-op: rows j>i are still zero at outer step i).
// o[i] = sum_t gm[i][t] * o_cur[t], i = 127..0 -> independent per column d.
// One thread per column; column in LDS; per-row gm as two 64-bit masks
// (wave-uniform -> LDS broadcast). 1/cnt scaling fused into the load.
// ---------------------------------------------------------------------------
__global__ __launch_bounds__(64) void k_recur(const float* __restrict__ P,
                                              const int* __restrict__ gm,
                                              const int* __restrict__ cnt,
                                              float* __restrict__ out) {
    __shared__ float o[NTAG][64];                // 32 KB
    __shared__ unsigned long long msk[NTAG][2];  // 2 KB
    __shared__ float inv[NTAG];
    const int tid = threadIdx.x;  // 0..63
    const int col = blockIdx.x * 64 + tid;

    for (int r = tid; r < NTAG; r += 64) {
        unsigned long long m0 = 0ull, m1 = 0ull;
        const int* row = gm + r * NTAG;
        for (int t = 0; t < 64; ++t)
            if (row[t] != 0) m0 |= (1ull << t);
        for (int t = 64; t < NTAG; ++t)
            if (row[t] != 0) m1 |= (1ull << (t - 64));
        msk[r][0] = m0;
        msk[r][1] = m1;
        inv[r] = 1.0f / (float)cnt[r];
    }
    __syncthreads();

    for (int t = 0; t < NTAG; ++t)
        o[t][tid] = P[(size_t)t * DDIM + col] * inv[t];

    for (int i = NTAG - 1; i >= 0; --i) {
        unsigned long long m0 = msk[i][0], m1 = msk[i][1];
        float a = 0.f, b = 0.f;
        while (m0) {
            const int t = __ffsll((unsigned long long)m0) - 1;
            m0 &= (m0 - 1);
            a += o[t][tid];
        }
        while (m1) {
            const int t = __ffsll((unsigned long long)m1) + 63;
            m1 &= (m1 - 1);
            b += o[t][tid];
        }
        o[i][tid] = a + b;
    }

    for (int i = 0; i < NTAG; ++i)
        out[(size_t)i * DDIM + col] = o[i][tid];
}

// ---------------------------------------------------------------------------
extern "C" void kernel_launch(void* const* d_in, const int* in_sizes, int n_in,
                              void* d_out, int out_size, void* d_ws, size_t ws_size,
                              hipStream_t stream) {
    const float* inp = (const float*)d_in[0];  // (N, D)
    const float* t2t = (const float*)d_in[1];  // (T, N)
    const int* gm = (const int*)d_in[2];       // (T, T)
    float* out = (float*)d_out;                // (T, D)

    char* ws = (char*)d_ws;
    float* P = (float*)ws;                     // 524288 B
    int* cnt = (int*)(ws + 524288);            // 512 B
    int* lastTag = (int*)(ws + 524288 + 512);  // 131072 B

    // Re-init every call (graph replays reuse d_ws).
    hipMemsetAsync(P, 0, 524288 + 512, stream);
    hipMemsetAsync(lastTag, 0xFF, NTOK * sizeof(int), stream);  // -1

    k_lasttag<<<256, 256, 0, stream>>>(t2t, lastTag);
    k_count<<<NTOK / TOK_CHUNK, 256, 0, stream>>>(lastTag, cnt);
    k_segsum<<<NTOK / TOKS_PER_BLK, 256, 0, stream>>>(inp, lastTag, P);
    k_recur<<<DDIM / 64, 64, 0, stream>>>(P, gm, cnt, out);
}

// Round 3
// 103.291 us; speedup vs baseline: 1.7918x; 1.0619x over previous
//
#include <hip/hip_runtime.h>

// Problem constants (B=1): inputs (N=32768, D=1024) f32, tag_to_token (T=128, N) f32,
// gat_mask (T, T) i32. Output (T, D) f32.
#define NTOK 32768
#define NTAG 128
#define DDIM 1024
#define TOKS_PER_BLK 32
#define ROWS_PER_CHUNK 16
#define TOK_CHUNK 1024  // tokens per block-column in k_prep / k_finallt

// ws layout
//   P       : 128*1024 f32   = 524288 B   (unscaled per-tag sums)
//   cnt     : 128 i32        = 512 B
//   lastTag : 32768 i32      = 131072 B
//   partLT  : 8*32768 i32    = 1 MB       (per-row-chunk partial last-tag max)

// ---------------------------------------------------------------------------
// Kernel 1: (a) zero P and cnt with plain stores (replaces hipMemsetAsync —
// the fill dispatches dominated round 2's profile), and (b) compute partial
// lastTag over this block's 16 t2t rows for 1024 tokens -> partLT (plain
// int4 stores, no atomics, no init dependency).
// Math fact: deduce_direct_string's temp[i][n] is 1 iff i is the LAST covering
// tag of n (for ANY 0/1 coverage), so normalized t2t is one-hot / cnt[tag].
// ---------------------------------------------------------------------------
__global__ __launch_bounds__(256) void k_prep(const float* __restrict__ t2t,
                                              float* __restrict__ P,
                                              int* __restrict__ cnt,
                                              int* __restrict__ partLT) {
    const int tid = threadIdx.x;
    // (a) zero P (131072 floats over 65536 threads -> one float2 each) + cnt
    const int gid = blockIdx.x * 256 + tid;
    reinterpret_cast<float2*>(P)[gid] = make_float2(0.f, 0.f);
    if (blockIdx.x == 0 && tid < NTAG) cnt[tid] = 0;

    // (b) partial last-tag over 16 rows x 1024 tokens
    const int tokChunk = blockIdx.x & 31;  // 32 token chunks
    const int rowChunk = blockIdx.x >> 5;  // 8 row chunks
    const int n0 = tokChunk * TOK_CHUNK + tid * 4;
    const int j0 = rowChunk * ROWS_PER_CHUNK;
    int l0 = -1, l1 = -1, l2 = -1, l3 = -1;
#pragma unroll
    for (int jj = 0; jj < ROWS_PER_CHUNK; ++jj) {
        const int j = j0 + jj;
        const float4 v = *reinterpret_cast<const float4*>(t2t + (size_t)j * NTOK + n0);
        if (v.x > 0.f) l0 = j;
        if (v.y > 0.f) l1 = j;
        if (v.z > 0.f) l2 = j;
        if (v.w > 0.f) l3 = j;
    }
    *reinterpret_cast<int4*>(partLT + (size_t)rowChunk * NTOK + n0) =
        make_int4(l0, l1, l2, l3);
}

// ---------------------------------------------------------------------------
// Kernel 2: reduce partLT over the 8 row chunks -> lastTag, and histogram
// into cnt (LDS histogram, one global atomicAdd per tag per block).
// ---------------------------------------------------------------------------
__global__ __launch_bounds__(256) void k_finallt(const int* __restrict__ partLT,
                                                 int* __restrict__ lastTag,
                                                 int* __restrict__ cnt) {
    __shared__ int hist[NTAG];
    const int tid = threadIdx.x;
    if (tid < NTAG) hist[tid] = 0;
    __syncthreads();

    const int n0 = blockIdx.x * TOK_CHUNK + tid * 4;
    int4 m = make_int4(-1, -1, -1, -1);
#pragma unroll
    for (int c = 0; c < 8; ++c) {
        const int4 v = *reinterpret_cast<const int4*>(partLT + (size_t)c * NTOK + n0);
        m.x = max(m.x, v.x);
        m.y = max(m.y, v.y);
        m.z = max(m.z, v.z);
        m.w = max(m.w, v.w);
    }
    *reinterpret_cast<int4*>(lastTag + n0) = m;
    if (m.x >= 0) atomicAdd(&hist[m.x], 1);
    if (m.y >= 0) atomicAdd(&hist[m.y], 1);
    if (m.z >= 0) atomicAdd(&hist[m.z], 1);
    if (m.w >= 0) atomicAdd(&hist[m.w], 1);
    __syncthreads();
    if (tid < NTAG && hist[tid] > 0) atomicAdd(&cnt[tid], hist[tid]);
}

// ---------------------------------------------------------------------------
// Kernel 3: segmented sum. Each block owns 32 tokens x all 1024 columns
// (thread t -> cols 4t..4t+3, float4); grid = 1024 -> 16 waves/CU. Tokens
// walked in order; on a tag change the run's partial sum is flushed with 4
// atomicAdds into P[tag][col] (P pre-zeroed in k_prep). For nested/contiguous
// data each chunk is 1-2 runs -> atomics rare and uncontended.
// ---------------------------------------------------------------------------
__global__ __launch_bounds__(256) void k_segsum(const float* __restrict__ inp,
                                                const int* __restrict__ lastTag,
                                                float* __restrict__ P) {
    __shared__ int tags[TOKS_PER_BLK];
    const int tid = threadIdx.x;
    const int n0 = blockIdx.x * TOKS_PER_BLK;
    if (tid < TOKS_PER_BLK) tags[tid] = lastTag[n0 + tid];
    __syncthreads();

    const int col = tid * 4;
    float4 acc = make_float4(0.f, 0.f, 0.f, 0.f);
    int cur = tags[0];
    for (int k = 0; k < TOKS_PER_BLK; ++k) {
        const int tg = tags[k];
        if (tg != cur) {  // wave-uniform branch (tags uniform across lanes)
            if (cur >= 0) {
                float* p = P + (size_t)cur * DDIM + col;
                atomicAdd(p + 0, acc.x);
                atomicAdd(p + 1, acc.y);
                atomicAdd(p + 2, acc.z);
                atomicAdd(p + 3, acc.w);
            }
            acc = make_float4(0.f, 0.f, 0.f, 0.f);
            cur = tg;
        }
        if (tg >= 0) {
            const float4 v =
                *reinterpret_cast<const float4*>(inp + (size_t)(n0 + k) * DDIM + col);
            acc.x += v.x;
            acc.y += v.y;
            acc.z += v.z;
            acc.w += v.w;
        }
    }
    if (cur >= 0) {
        float* p = P + (size_t)cur * DDIM + col;
        atomicAdd(p + 0, acc.x);
        atomicAdd(p + 1, acc.y);
        atomicAdd(p + 2, acc.z);
        atomicAdd(p + 3, acc.w);
    }
}

// ---------------------------------------------------------------------------
// Kernel 4: triangular recurrence. deduce_child(gm) == gm for ANY input
// (inner loop provably a no-op: rows j>i are still zero at outer step i).
// o[i] = sum_t gm[i][t] * o_cur[t], i = 127..0 -> independent per column d.
// One thread per column; column in LDS; per-row gm as two 64-bit masks
// (wave-uniform -> LDS broadcast). 1/cnt scaling fused into the load.
// ---------------------------------------------------------------------------
__global__ __launch_bounds__(64) void k_recur(const float* __restrict__ P,
                                              const int* __restrict__ gm,
                                              const int* __restrict__ cnt,
                                              float* __restrict__ out) {
    __shared__ float o[NTAG][64];                // 32 KB
    __shared__ unsigned long long msk[NTAG][2];  // 2 KB
    __shared__ float inv[NTAG];
    const int tid = threadIdx.x;  // 0..63
    const int col = blockIdx.x * 64 + tid;

    for (int r = tid; r < NTAG; r += 64) {
        unsigned long long m0 = 0ull, m1 = 0ull;
        const int* row = gm + r * NTAG;
        for (int t = 0; t < 64; ++t)
            if (row[t] != 0) m0 |= (1ull << t);
        for (int t = 64; t < NTAG; ++t)
            if (row[t] != 0) m1 |= (1ull << (t - 64));
        msk[r][0] = m0;
        msk[r][1] = m1;
        inv[r] = 1.0f / (float)cnt[r];
    }
    __syncthreads();

    for (int t = 0; t < NTAG; ++t)
        o[t][tid] = P[(size_t)t * DDIM + col] * inv[t];

    for (int i = NTAG - 1; i >= 0; --i) {
        unsigned long long m0 = msk[i][0], m1 = msk[i][1];
        float a = 0.f, b = 0.f;
        while (m0) {
            const int t = __ffsll((unsigned long long)m0) - 1;
            m0 &= (m0 - 1);
            a += o[t][tid];
        }
        while (m1) {
            const int t = __ffsll((unsigned long long)m1) + 63;
            m1 &= (m1 - 1);
            b += o[t][tid];
        }
        o[i][tid] = a + b;
    }

    for (int i = 0; i < NTAG; ++i)
        out[(size_t)i * DDIM + col] = o[i][tid];
}

// ---------------------------------------------------------------------------
extern "C" void kernel_launch(void* const* d_in, const int* in_sizes, int n_in,
                              void* d_out, int out_size, void* d_ws, size_t ws_size,
                              hipStream_t stream) {
    const float* inp = (const float*)d_in[0];  // (N, D)
    const float* t2t = (const float*)d_in[1];  // (T, N)
    const int* gm = (const int*)d_in[2];       // (T, T)
    float* out = (float*)d_out;                // (T, D)

    char* ws = (char*)d_ws;
    float* P = (float*)ws;                            // 524288 B
    int* cnt = (int*)(ws + 524288);                   // 512 B
    int* lastTag = (int*)(ws + 524288 + 512);         // 131072 B
    int* partLT = (int*)(ws + 524288 + 512 + 131072); // 1 MB

    k_prep<<<256, 256, 0, stream>>>(t2t, P, cnt, partLT);
    k_finallt<<<NTOK / TOK_CHUNK, 256, 0, stream>>>(partLT, lastTag, cnt);
    k_segsum<<<NTOK / TOKS_PER_BLK, 256, 0, stream>>>(inp, lastTag, P);
    k_recur<<<DDIM / 64, 64, 0, stream>>>(P, gm, cnt, out);
}